// Round 1
// baseline (125.648 us; speedup 1.0000x reference)
//
#include <hip/hip_runtime.h>
#include <hip/hip_bf16.h>

// Full attention fwd: N=4, L=S=2048, H=8, D=64, fp32 in/out.
// qk = einsum('nlhd,nshd->nlsh'); softmax over S with 1/sqrt(D); out = attn @ V.
// Flash-style: block = 4 waves = 256 thr, QBLK=64 (16 q-rows/wave), KVBLK=64.
// bf16 MFMA 16x16x32, fp32 softmax/accum.

typedef __bf16 bf16x8 __attribute__((ext_vector_type(8)));
typedef float f32x4 __attribute__((ext_vector_type(4)));

#define N_ 4
#define L_ 2048
#define S_ 2048
#define H_ 8
#define D_ 64
#define QBLK 64
#define KVBLK 64
#define SCALE 0.125f   // 1/sqrt(64)

__global__ __launch_bounds__(256) void fattn_kernel(
    const float* __restrict__ Q, const float* __restrict__ K,
    const float* __restrict__ V, float* __restrict__ Out)
{
    // K tile [s][d] row-major, XOR-swizzled 16B slots (row = 128B -> 32-way conflict otherwise)
    __shared__ __align__(16) __bf16 Klds[KVBLK * 64];
    // V tile transposed [d][s], same swizzle
    __shared__ __align__(16) __bf16 Vlds[64 * KVBLK];
    // per-wave P tile [q][s] 16x64, swizzled
    __shared__ __align__(16) __bf16 Plds[4][16 * 64];

    const int tid  = threadIdx.x;
    const int wave = tid >> 6;
    const int lane = tid & 63;
    const int g    = lane >> 4;   // 16-lane group 0..3
    const int lr   = lane & 15;

    const int bid = blockIdx.x;
    const int nh  = bid >> 5;     // n*H + h   (32 q-tiles per (n,h))
    const int qt  = bid & 31;
    const int n   = nh >> 3;
    const int h   = nh & 7;
    const int q0  = qt * QBLK;

    const size_t head_off = ((size_t)n * L_ * H_ + h) * D_;
    const float* Qp = Q + head_off;
    const float* Kp = K + head_off;
    const float* Vp = V + head_off;
    float*       Op = Out + head_off;
    const int rstride = H_ * D_;  // 512 floats between consecutive l/s rows

    // ---- Q fragments in registers (A operand, 16x32 per k-slice), scaled ----
    bf16x8 qf[2];
    {
        const int qrow = q0 + wave * 16 + lr;
        const float* base = Qp + (size_t)qrow * rstride;
#pragma unroll
        for (int ks = 0; ks < 2; ++ks) {
            const float* p = base + ks * 32 + g * 8;
            float4 a = *(const float4*)p;
            float4 b = *(const float4*)(p + 4);
            bf16x8 v;
            v[0] = (__bf16)(a.x * SCALE); v[1] = (__bf16)(a.y * SCALE);
            v[2] = (__bf16)(a.z * SCALE); v[3] = (__bf16)(a.w * SCALE);
            v[4] = (__bf16)(b.x * SCALE); v[5] = (__bf16)(b.y * SCALE);
            v[6] = (__bf16)(b.z * SCALE); v[7] = (__bf16)(b.w * SCALE);
            qf[ks] = v;
        }
    }

    // ---- online-softmax state: rows q = g*4 + r (replicated across 16-lane group) ----
    float m_r[4], lsum[4];
    f32x4 oacc[4];
#pragma unroll
    for (int r = 0; r < 4; ++r) { m_r[r] = -1e30f; lsum[r] = 0.f; }
#pragma unroll
    for (int t = 0; t < 4; ++t) oacc[t] = (f32x4){0.f, 0.f, 0.f, 0.f};

    for (int kv = 0; kv < S_ / KVBLK; ++kv) {
        const int s0 = kv * KVBLK;
        __syncthreads();   // previous tile's LDS reads done

        // ---- stage K: 64x64 fp32 -> bf16, row-major [s][d], swizzled ----
#pragma unroll
        for (int it = 0; it < 2; ++it) {
            const int c    = it * 256 + tid;        // 0..511 chunks of 8
            const int row  = c >> 3;
            const int slot = c & 7;
            const float* p = Kp + (size_t)(s0 + row) * rstride + slot * 8;
            float4 a = *(const float4*)p;
            float4 b = *(const float4*)(p + 4);
            bf16x8 v;
            v[0] = (__bf16)a.x; v[1] = (__bf16)a.y; v[2] = (__bf16)a.z; v[3] = (__bf16)a.w;
            v[4] = (__bf16)b.x; v[5] = (__bf16)b.y; v[6] = (__bf16)b.z; v[7] = (__bf16)b.w;
            *(bf16x8*)&Klds[row * 64 + ((slot ^ (row & 7)) * 8)] = v;
        }
        // ---- stage V transposed: Vlds[d][s], swizzled; coalesced row reads ----
#pragma unroll
        for (int it = 0; it < 2; ++it) {
            const int c     = it * 256 + tid;
            const int d     = c & 63;
            const int chunk = c >> 6;               // 8 s-values per chunk
            const float* p  = Vp + (size_t)(s0 + chunk * 8) * rstride + d;
            bf16x8 v;
#pragma unroll
            for (int j = 0; j < 8; ++j) v[j] = (__bf16)p[j * rstride];
            *(bf16x8*)&Vlds[d * 64 + ((chunk ^ (d & 7)) * 8)] = v;
        }
        __syncthreads();

        // ---- QK^T: S-tile 16x64 per wave; sacc[t] holds s in [16t,16t+16) ----
        f32x4 sacc[4];
#pragma unroll
        for (int t = 0; t < 4; ++t) sacc[t] = (f32x4){0.f, 0.f, 0.f, 0.f};
#pragma unroll
        for (int t = 0; t < 4; ++t) {
#pragma unroll
            for (int ks = 0; ks < 2; ++ks) {
                const int row  = t * 16 + lr;       // s-row in K tile
                const int slot = ks * 4 + g;        // d-slot
                bf16x8 kf = *(const bf16x8*)&Klds[row * 64 + ((slot ^ (row & 7)) * 8)];
                sacc[t] = __builtin_amdgcn_mfma_f32_16x16x32_bf16(qf[ks], kf, sacc[t], 0, 0, 0);
            }
        }

        // ---- online softmax (rows replicated across 16-lane groups) ----
#pragma unroll
        for (int r = 0; r < 4; ++r) {
            float tm = fmaxf(fmaxf(sacc[0][r], sacc[1][r]), fmaxf(sacc[2][r], sacc[3][r]));
#pragma unroll
            for (int msk = 1; msk < 16; msk <<= 1) tm = fmaxf(tm, __shfl_xor(tm, msk, 64));
            const float mnew  = fmaxf(m_r[r], tm);
            const float alpha = __expf(m_r[r] - mnew);   // first tile: exp(-1e30)=0
            m_r[r] = mnew;
            float psum = 0.f;
#pragma unroll
            for (int t = 0; t < 4; ++t) {
                const float p = __expf(sacc[t][r] - mnew);
                sacc[t][r] = p;
                psum += p;
            }
#pragma unroll
            for (int msk = 1; msk < 16; msk <<= 1) psum += __shfl_xor(psum, msk, 64);
            lsum[r] = lsum[r] * alpha + psum;
#pragma unroll
            for (int t = 0; t < 4; ++t) oacc[t][r] *= alpha;
        }

        // ---- P -> bf16 -> wave-private LDS (re-layout accumulator -> A-frag) ----
        __bf16* Pw = Plds[wave];
#pragma unroll
        for (int t = 0; t < 4; ++t) {
            const int s    = t * 16 + lr;
            const int slot = s >> 3;
#pragma unroll
            for (int r = 0; r < 4; ++r) {
                const int q = g * 4 + r;
                Pw[q * 64 + ((slot ^ (q & 7)) * 8) + (s & 7)] = (__bf16)sacc[t][r];
            }
        }

        // ---- PV: O += P (16x64) x V (64x64) ----
        bf16x8 pf[2];
#pragma unroll
        for (int kt = 0; kt < 2; ++kt) {
            const int slot = kt * 4 + g;            // s-slot
            pf[kt] = *(const bf16x8*)&Pw[lr * 64 + ((slot ^ (lr & 7)) * 8)];
        }
#pragma unroll
        for (int td = 0; td < 4; ++td) {
#pragma unroll
            for (int kt = 0; kt < 2; ++kt) {
                const int drow = td * 16 + lr;      // d-row in Vt tile
                const int slot = kt * 4 + g;        // s-slot
                bf16x8 vf = *(const bf16x8*)&Vlds[drow * 64 + ((slot ^ (drow & 7)) * 8)];
                oacc[td] = __builtin_amdgcn_mfma_f32_16x16x32_bf16(pf[kt], vf, oacc[td], 0, 0, 0);
            }
        }
    }

    // ---- epilogue: normalize and store fp32 ----
    float inv[4];
#pragma unroll
    for (int r = 0; r < 4; ++r) inv[r] = 1.0f / lsum[r];
    const int qbase = q0 + wave * 16 + g * 4;
#pragma unroll
    for (int td = 0; td < 4; ++td) {
#pragma unroll
        for (int r = 0; r < 4; ++r) {
            Op[(size_t)(qbase + r) * rstride + td * 16 + lr] = oacc[td][r] * inv[r];
        }
    }
}

extern "C" void kernel_launch(void* const* d_in, const int* in_sizes, int n_in,
                              void* d_out, int out_size, void* d_ws, size_t ws_size,
                              hipStream_t stream) {
    const float* Q = (const float*)d_in[0];
    const float* K = (const float*)d_in[1];
    const float* V = (const float*)d_in[2];
    float* Out = (float*)d_out;
    dim3 grid(N_ * H_ * (L_ / QBLK));   // 4*8*32 = 1024 blocks
    dim3 block(256);
    fattn_kernel<<<grid, block, 0, stream>>>(Q, K, V, Out);
}

// Round 2
// 76.938 us; speedup vs baseline: 1.6331x; 1.6331x over previous
//
#include <hip/hip_runtime.h>
#include <hip/hip_bf16.h>
#include <stdint.h>

// Full attention fwd: N=4, L=S=2048, H=8, D=64, fp32 in/out.
// Round 2: prepass K->bf16 [nh][s][d], V->bf16^T [nh][d][s] into d_ws;
// main kernel: QBLK=128 (4 waves x 32 q-rows), KVBLK=64, swapped QK^T
// (lane-local softmax rows), exp2 domain, defer-max, global_load_lds
// double-buffered staging with pre-swizzled source addresses.

typedef __bf16 bf16x8 __attribute__((ext_vector_type(8)));
typedef __bf16 bf16x4 __attribute__((ext_vector_type(4)));
typedef float f32x4 __attribute__((ext_vector_type(4)));

#define N_ 4
#define L_ 2048
#define S_ 2048
#define H_ 8
#define D_ 64
#define NH 32
#define QBLK 128
#define KVBLK 64
#define NKV (S_ / KVBLK)
#define HEAD_ELEMS (S_ * D_)            // 131072 bf16 per (n,h) plane
#define SCALE_LOG2E 0.18033688011112042f // (1/sqrt(64)) * log2(e)

typedef const __attribute__((address_space(1))) uint8_t* gptr_t;
typedef __attribute__((address_space(3))) uint8_t* lptr_t;
#define GLOAD16(g, l) __builtin_amdgcn_global_load_lds((gptr_t)(g), (lptr_t)(l), 16, 0, 0)

// ---------------- prepass: K fp32 [n][s][h][d] -> bf16 [n*h][s][d] ----------------
__global__ __launch_bounds__(256) void prep_k(const float* __restrict__ K,
                                              __bf16* __restrict__ Kb) {
    const int chunk = blockIdx.x * 256 + threadIdx.x;   // float4 index
    const int n     = chunk >> 18;                      // 262144 float4 per n
    const int rem   = chunk & 262143;
    const int s     = rem >> 7;
    const int r2    = rem & 127;
    const int h     = r2 >> 4;
    const int dslot = r2 & 15;
    float4 v = *(const float4*)(K + (size_t)chunk * 4);
    bf16x4 o = { (__bf16)v.x, (__bf16)v.y, (__bf16)v.z, (__bf16)v.w };
    *(bf16x4*)(Kb + ((size_t)(n * 8 + h) * 2048 + s) * 64 + dslot * 4) = o;
}

// ------------- prepass: V fp32 [n][s][h][d] -> bf16 transposed [n*h][d][s] -------------
__global__ __launch_bounds__(256) void prep_v(const float* __restrict__ V,
                                              __bf16* __restrict__ Vt) {
    __shared__ __align__(16) __bf16 T[64 * 64];
    const int tid = threadIdx.x;
    const int bid = blockIdx.x;          // nh*32 + s-chunk
    const int nh  = bid >> 5;
    const int n   = nh >> 3, h = nh & 7;
    const int s0  = (bid & 31) * 64;
#pragma unroll
    for (int it = 0; it < 16; ++it) {
        const int idx = it * 256 + tid;
        const int sl  = idx >> 6;        // s within tile
        const int d   = idx & 63;
        float v = V[(size_t)(n * 2048 + s0 + sl) * 512 + h * 64 + d];
        T[d * 64 + (((sl >> 3) ^ (d & 7)) * 8) + (sl & 7)] = (__bf16)v;
    }
    __syncthreads();
#pragma unroll
    for (int it = 0; it < 2; ++it) {
        const int idx = it * 256 + tid;
        const int d   = idx >> 3;
        const int sc  = idx & 7;
        bf16x8 v = *(const bf16x8*)&T[d * 64 + ((sc ^ (d & 7)) * 8)];
        *(bf16x8*)(Vt + (size_t)nh * HEAD_ELEMS + (size_t)d * 2048 + s0 + sc * 8) = v;
    }
}

// ---------------- main attention kernel ----------------
__global__ __launch_bounds__(256, 2) void fattn(const float* __restrict__ Q,
                                                const __bf16* __restrict__ Kb,
                                                const __bf16* __restrict__ Vt,
                                                float* __restrict__ Out) {
    // double-buffered K/V tiles (content XOR-swizzled at 16B slot granularity)
    __shared__ __align__(16) __bf16 Kl[2][KVBLK * 64];
    __shared__ __align__(16) __bf16 Vl[2][64 * KVBLK];
    __shared__ __align__(16) __bf16 Pl[4][2 * 16 * 64];   // per-wave P, 2 q-subtiles

    const int tid  = threadIdx.x;
    const int wave = tid >> 6;
    const int lane = tid & 63;
    const int g    = lane >> 4;
    const int lr   = lane & 15;

    int bid = blockIdx.x;
    bid = (bid & 7) * 64 + (bid >> 3);   // XCD-aware swizzle (512 % 8 == 0 -> bijective)
    const int nh = bid >> 4;             // 16 q-blocks per (n,h)
    const int qt = bid & 15;
    const int n  = nh >> 3, h = nh & 7;
    const int q0 = qt * QBLK;

    const float*  Qp = Q   + (size_t)n * 1048576 + h * 64;
    float*        Op = Out + (size_t)n * 1048576 + h * 64;
    const __bf16* Kh = Kb + (size_t)nh * HEAD_ELEMS;
    const __bf16* Vh = Vt + (size_t)nh * HEAD_ELEMS;

    // staged-source offsets: LDS linear, source pre-swizzled (slot ^ (row&7))
    int koff[2], voff[2], ldst[2];
#pragma unroll
    for (int c = 0; c < 2; ++c) {
        const int slot = wave * 128 + c * 64 + lane;
        const int row  = slot >> 3, sc = slot & 7;
        koff[c] = row * 64   + ((sc ^ (row & 7)) * 8);
        voff[c] = row * 2048 + ((sc ^ (row & 7)) * 8);   // row == d for V^T
        ldst[c] = (wave * 128 + c * 64) * 8;             // bf16 elems (wave-uniform)
    }

    // Q fragments (B operand of swapped QK^T), scaled by 1/sqrt(D)*log2(e)
    bf16x8 qf[2][2];
#pragma unroll
    for (int m = 0; m < 2; ++m) {
        const float* qp = Qp + (size_t)(q0 + wave * 32 + m * 16 + lr) * 512;
#pragma unroll
        for (int ks = 0; ks < 2; ++ks) {
            float4 a = *(const float4*)(qp + ks * 32 + g * 8);
            float4 b = *(const float4*)(qp + ks * 32 + g * 8 + 4);
            bf16x8 v;
            v[0] = (__bf16)(a.x * SCALE_LOG2E); v[1] = (__bf16)(a.y * SCALE_LOG2E);
            v[2] = (__bf16)(a.z * SCALE_LOG2E); v[3] = (__bf16)(a.w * SCALE_LOG2E);
            v[4] = (__bf16)(b.x * SCALE_LOG2E); v[5] = (__bf16)(b.y * SCALE_LOG2E);
            v[6] = (__bf16)(b.z * SCALE_LOG2E); v[7] = (__bf16)(b.w * SCALE_LOG2E);
            qf[m][ks] = v;
        }
    }

    auto stage = [&](int b, int kv) {
        const __bf16* kbase = Kh + (size_t)kv * 4096;
        const __bf16* vbase = Vh + kv * 64;
#pragma unroll
        for (int c = 0; c < 2; ++c) {
            GLOAD16(kbase + koff[c], &Kl[b][ldst[c]]);
            GLOAD16(vbase + voff[c], &Vl[b][ldst[c]]);
        }
    };

    float m_r[2]  = {-1e30f, -1e30f};
    float lsum[2] = {0.f, 0.f};
    f32x4 oacc[2][4];
#pragma unroll
    for (int m = 0; m < 2; ++m)
#pragma unroll
        for (int t = 0; t < 4; ++t) oacc[m][t] = (f32x4){0.f, 0.f, 0.f, 0.f};

    stage(0, 0);
    __syncthreads();   // drains vmcnt(0): buffer 0 ready
    int buf = 0;

    for (int kv = 0; kv < NKV; ++kv) {
        if (kv + 1 < NKV) stage(buf ^ 1, kv + 1);   // prefetch next tile

        // ---- QK^T (swapped: A=K rows=s, B=Q cols=q) ----
        f32x4 sacc[2][4];
#pragma unroll
        for (int m = 0; m < 2; ++m)
#pragma unroll
            for (int t = 0; t < 4; ++t) sacc[m][t] = (f32x4){0.f, 0.f, 0.f, 0.f};
#pragma unroll
        for (int t = 0; t < 4; ++t) {
#pragma unroll
            for (int ks = 0; ks < 2; ++ks) {
                bf16x8 kf = *(const bf16x8*)&Kl[buf][(t * 16 + lr) * 64 + (((ks * 4 + g) ^ (lr & 7)) * 8)];
                sacc[0][t] = __builtin_amdgcn_mfma_f32_16x16x32_bf16(kf, qf[0][ks], sacc[0][t], 0, 0, 0);
                sacc[1][t] = __builtin_amdgcn_mfma_f32_16x16x32_bf16(kf, qf[1][ks], sacc[1][t], 0, 0, 0);
            }
        }

        // ---- softmax: lane owns row q=lr, s = t*16 + g*4 + r (log2 domain) ----
#pragma unroll
        for (int m = 0; m < 2; ++m) {
            float tm = fmaxf(fmaxf(fmaxf(sacc[m][0][0], sacc[m][0][1]), fmaxf(sacc[m][0][2], sacc[m][0][3])),
                             fmaxf(fmaxf(sacc[m][1][0], sacc[m][1][1]), fmaxf(sacc[m][1][2], sacc[m][1][3])));
            tm = fmaxf(tm, fmaxf(fmaxf(fmaxf(sacc[m][2][0], sacc[m][2][1]), fmaxf(sacc[m][2][2], sacc[m][2][3])),
                                 fmaxf(fmaxf(sacc[m][3][0], sacc[m][3][1]), fmaxf(sacc[m][3][2], sacc[m][3][3]))));
            tm = fmaxf(tm, __shfl_xor(tm, 16, 64));
            tm = fmaxf(tm, __shfl_xor(tm, 32, 64));
            if (!__all(tm <= m_r[m] + 8.0f)) {      // defer-max (T13)
                const float mnew = fmaxf(m_r[m], tm);
                const float al   = __builtin_amdgcn_exp2f(m_r[m] - mnew);
                m_r[m] = mnew;
                lsum[m] *= al;
#pragma unroll
                for (int t = 0; t < 4; ++t) {
                    oacc[m][t][0] *= al; oacc[m][t][1] *= al;
                    oacc[m][t][2] *= al; oacc[m][t][3] *= al;
                }
            }
            float ps = 0.f;
#pragma unroll
            for (int t = 0; t < 4; ++t) {
#pragma unroll
                for (int r = 0; r < 4; ++r) {
                    const float p = __builtin_amdgcn_exp2f(sacc[m][t][r] - m_r[m]);
                    sacc[m][t][r] = p;
                    ps += p;
                }
            }
            lsum[m] += ps;   // group-partial; reduced across g at epilogue
            // P -> LDS (swizzled b64 writes; wave-private)
#pragma unroll
            for (int t = 0; t < 4; ++t) {
                bf16x4 pk4 = { (__bf16)sacc[m][t][0], (__bf16)sacc[m][t][1],
                               (__bf16)sacc[m][t][2], (__bf16)sacc[m][t][3] };
                *(bf16x4*)&Pl[wave][m * 1024 + lr * 64 + (((2 * t + (g >> 1)) ^ (lr & 7)) * 8) + (g & 1) * 4] = pk4;
            }
        }

        // ---- PV (swapped: O^T = V^T * P^T; A=V^T rows=d, B=P^T cols=q) ----
        bf16x8 pf[2][2];
#pragma unroll
        for (int m = 0; m < 2; ++m)
#pragma unroll
            for (int kt = 0; kt < 2; ++kt)
                pf[m][kt] = *(const bf16x8*)&Pl[wave][m * 1024 + lr * 64 + (((kt * 4 + g) ^ (lr & 7)) * 8)];
#pragma unroll
        for (int td = 0; td < 4; ++td) {
#pragma unroll
            for (int kt = 0; kt < 2; ++kt) {
                bf16x8 vf = *(const bf16x8*)&Vl[buf][(td * 16 + lr) * 64 + (((kt * 4 + g) ^ (lr & 7)) * 8)];
                oacc[0][td] = __builtin_amdgcn_mfma_f32_16x16x32_bf16(vf, pf[0][kt], oacc[0][td], 0, 0, 0);
                oacc[1][td] = __builtin_amdgcn_mfma_f32_16x16x32_bf16(vf, pf[1][kt], oacc[1][td], 0, 0, 0);
            }
        }

        __syncthreads();   // drains vmcnt(0): next buffer ready, this buffer free
        buf ^= 1;
    }

    // ---- epilogue: reduce lsum across groups, normalize, store fp32 ----
#pragma unroll
    for (int m = 0; m < 2; ++m) {
        float ls = lsum[m];
        ls += __shfl_xor(ls, 16, 64);
        ls += __shfl_xor(ls, 32, 64);
        const float inv = 1.0f / ls;
        float* op = Op + (size_t)(q0 + wave * 32 + m * 16 + lr) * 512;
#pragma unroll
        for (int td = 0; td < 4; ++td) {
            float4 o = { oacc[m][td][0] * inv, oacc[m][td][1] * inv,
                         oacc[m][td][2] * inv, oacc[m][td][3] * inv };
            *(float4*)(op + td * 16 + g * 4) = o;
        }
    }
}

extern "C" void kernel_launch(void* const* d_in, const int* in_sizes, int n_in,
                              void* d_out, int out_size, void* d_ws, size_t ws_size,
                              hipStream_t stream) {
    const float* Q = (const float*)d_in[0];
    const float* K = (const float*)d_in[1];
    const float* V = (const float*)d_in[2];
    float* Out = (float*)d_out;
    __bf16* Kb = (__bf16*)d_ws;
    __bf16* Vt = Kb + (size_t)NH * HEAD_ELEMS;   // 8 MB each, 16 MB total

    prep_k<<<dim3(4096), dim3(256), 0, stream>>>(K, Kb);
    prep_v<<<dim3(1024), dim3(256), 0, stream>>>(V, Vt);
    fattn <<<dim3(512),  dim3(256), 0, stream>>>(Q, Kb, Vt, Out);
}

// Round 3
// 75.535 us; speedup vs baseline: 1.6634x; 1.0186x over previous
//
#include <hip/hip_runtime.h>
#include <hip/hip_bf16.h>
#include <stdint.h>

// Full attention fwd: N=4, L=S=2048, H=8, D=64, fp32 in/out.
// Round 3: 32x32x16 MFMA, P kept fully in registers via cvt-pack +
// v_permlane32_swap_b32 (T12). No P-LDS. Swapped QK^T (lane owns q-column),
// swapped PV (O^T = V^T P^T). Double-buffered K/V staging via global_load_lds
// with pre-swizzled sources; bank-balanced read patterns. exp2 domain,
// defer-max (THR=8), XCD-aware block swizzle, setprio around MFMA clusters.

typedef __bf16 bf16x8 __attribute__((ext_vector_type(8)));
typedef __bf16 bf16x4 __attribute__((ext_vector_type(4)));
typedef float  f32x16 __attribute__((ext_vector_type(16)));

#define N_ 4
#define L_ 2048
#define S_ 2048
#define H_ 8
#define D_ 64
#define NH 32
#define QBLK 128
#define KVBLK 64
#define NKV (S_ / KVBLK)
#define HEAD_ELEMS (S_ * D_)             // 131072 bf16 per (n,h) plane
#define SCALE_LOG2E 0.18033688011112042f // (1/sqrt(64)) * log2(e)

typedef const __attribute__((address_space(1))) uint8_t* gptr_t;
typedef __attribute__((address_space(3))) uint8_t* lptr_t;
#define GLOAD16(g, l) __builtin_amdgcn_global_load_lds((gptr_t)(g), (lptr_t)(l), 16, 0, 0)

static __device__ __forceinline__ uint32_t pkbf(float lo, float hi) {
    uint16_t l = __builtin_bit_cast(uint16_t, (__bf16)lo);
    uint16_t h = __builtin_bit_cast(uint16_t, (__bf16)hi);
    return (uint32_t)l | ((uint32_t)h << 16);
}

// ---------------- prepass: K fp32 [n][s][h][d] -> bf16 [n*h][s][d] ----------------
__global__ __launch_bounds__(256) void prep_k(const float* __restrict__ K,
                                              __bf16* __restrict__ Kb) {
    const int chunk = blockIdx.x * 256 + threadIdx.x;   // float4 index
    const int n     = chunk >> 18;
    const int rem   = chunk & 262143;
    const int s     = rem >> 7;
    const int r2    = rem & 127;
    const int h     = r2 >> 4;
    const int dslot = r2 & 15;
    float4 v = *(const float4*)(K + (size_t)chunk * 4);
    bf16x4 o = { (__bf16)v.x, (__bf16)v.y, (__bf16)v.z, (__bf16)v.w };
    *(bf16x4*)(Kb + ((size_t)(n * 8 + h) * 2048 + s) * 64 + dslot * 4) = o;
}

// ------------- prepass: V fp32 [n][s][h][d] -> bf16 transposed [n*h][d][s] -------------
__global__ __launch_bounds__(256) void prep_v(const float* __restrict__ V,
                                              __bf16* __restrict__ Vt) {
    __shared__ __align__(16) __bf16 T[64 * 64];
    const int tid = threadIdx.x;
    const int bid = blockIdx.x;          // nh*32 + s-chunk
    const int nh  = bid >> 5;
    const int n   = nh >> 3, h = nh & 7;
    const int s0  = (bid & 31) * 64;
#pragma unroll
    for (int it = 0; it < 16; ++it) {
        const int idx = it * 256 + tid;
        const int sl  = idx >> 6;
        const int d   = idx & 63;
        float v = V[(size_t)(n * 2048 + s0 + sl) * 512 + h * 64 + d];
        T[d * 64 + (((sl >> 3) ^ (d & 7)) * 8) + (sl & 7)] = (__bf16)v;
    }
    __syncthreads();
#pragma unroll
    for (int it = 0; it < 2; ++it) {
        const int idx = it * 256 + tid;
        const int d   = idx >> 3;
        const int sc  = idx & 7;
        bf16x8 v = *(const bf16x8*)&T[d * 64 + ((sc ^ (d & 7)) * 8)];
        *(bf16x8*)(Vt + (size_t)nh * HEAD_ELEMS + (size_t)d * 2048 + s0 + sc * 8) = v;
    }
}

// ---------------- main attention kernel ----------------
__global__ __launch_bounds__(256, 2) void fattn(const float* __restrict__ Q,
                                                const __bf16* __restrict__ Kb,
                                                const __bf16* __restrict__ Vt,
                                                float* __restrict__ Out) {
    __shared__ __align__(16) __bf16 Kl[2][KVBLK * 64];   // [s][d], swizzled content
    __shared__ __align__(16) __bf16 Vl[2][64 * KVBLK];   // [d][s], swizzled content

    const int tid  = threadIdx.x;
    const int wave = tid >> 6;
    const int lane = tid & 63;
    const int hh   = lane >> 5;   // lane half
    const int c    = lane & 31;   // q-column within wave's 32-q tile

    int bid = blockIdx.x;
    bid = (bid & 7) * 64 + (bid >> 3);   // XCD swizzle (512 % 8 == 0 -> bijective)
    const int nh = bid >> 4;
    const int qt = bid & 15;
    const int n  = nh >> 3, hd = nh & 7;
    const int q0 = qt * QBLK;

    const float*  Qp = Q   + (size_t)n * 1048576 + hd * 64;
    float*        Op = Out + (size_t)n * 1048576 + hd * 64;
    const __bf16* Kh = Kb + (size_t)nh * HEAD_ELEMS;
    const __bf16* Vh = Vt + (size_t)nh * HEAD_ELEMS;

    // staging offsets: LDS linear, global source pre-swizzled (slot ^ (row&7))
    int koff[2], voff[2], ldst[2];
#pragma unroll
    for (int c2 = 0; c2 < 2; ++c2) {
        const int slot = wave * 128 + c2 * 64 + lane;
        const int row  = slot >> 3, sc = slot & 7;
        koff[c2] = row * 64   + ((sc ^ (row & 7)) * 8);
        voff[c2] = row * 2048 + ((sc ^ (row & 7)) * 8);   // row == d for V^T
        ldst[c2] = (wave * 128 + c2 * 64) * 8;            // wave-uniform bf16 base
    }

    // Q B-fragments (col = q = c, k = d = ks*16 + hh*8 + j), scaled
    bf16x8 qf[4];
    {
        const float* qp = Qp + (size_t)(q0 + wave * 32 + c) * 512;
#pragma unroll
        for (int ks = 0; ks < 4; ++ks) {
            float4 a = *(const float4*)(qp + ks * 16 + hh * 8);
            float4 b = *(const float4*)(qp + ks * 16 + hh * 8 + 4);
            bf16x8 v;
            v[0] = (__bf16)(a.x * SCALE_LOG2E); v[1] = (__bf16)(a.y * SCALE_LOG2E);
            v[2] = (__bf16)(a.z * SCALE_LOG2E); v[3] = (__bf16)(a.w * SCALE_LOG2E);
            v[4] = (__bf16)(b.x * SCALE_LOG2E); v[5] = (__bf16)(b.y * SCALE_LOG2E);
            v[6] = (__bf16)(b.z * SCALE_LOG2E); v[7] = (__bf16)(b.w * SCALE_LOG2E);
            qf[ks] = v;
        }
    }

    auto stage = [&](int b, int kv) {
        const __bf16* kbase = Kh + (size_t)kv * 4096;
        const __bf16* vbase = Vh + kv * 64;
#pragma unroll
        for (int c2 = 0; c2 < 2; ++c2) {
            GLOAD16(kbase + koff[c2], &Kl[b][ldst[c2]]);
            GLOAD16(vbase + voff[c2], &Vl[b][ldst[c2]]);
        }
    };

    float m_r = -1e30f, lsum = 0.f;
    f32x16 oacc[2];
#pragma unroll
    for (int dt = 0; dt < 2; ++dt)
#pragma unroll
        for (int r = 0; r < 16; ++r) oacc[dt][r] = 0.f;

    stage(0, 0);
    __syncthreads();
    int buf = 0;

    for (int kv = 0; kv < NKV; ++kv) {
        if (kv + 1 < NKV) stage(buf ^ 1, kv + 1);

        // ---- QK^T (swapped): sacc[st] = K-tile(32s x 64d) . Q^T, col = q = c ----
        f32x16 sacc[2];
#pragma unroll
        for (int st = 0; st < 2; ++st)
#pragma unroll
            for (int r = 0; r < 16; ++r) sacc[st][r] = 0.f;

        __builtin_amdgcn_s_setprio(1);
#pragma unroll
        for (int ks = 0; ks < 4; ++ks) {
#pragma unroll
            for (int st = 0; st < 2; ++st) {
                bf16x8 kf = *(const bf16x8*)&Kl[buf][(st * 32 + c) * 64 + (((ks * 2 + hh) ^ (c & 7)) * 8)];
                sacc[st] = __builtin_amdgcn_mfma_f32_32x32x16_bf16(kf, qf[ks], sacc[st], 0, 0, 0);
            }
        }
        __builtin_amdgcn_s_setprio(0);

        // ---- softmax: lane pair (c, c+32) owns q-column; log2 domain ----
        float tm = sacc[0][0];
#pragma unroll
        for (int r = 1; r < 16; ++r) tm = fmaxf(tm, sacc[0][r]);
#pragma unroll
        for (int r = 0; r < 16; ++r) tm = fmaxf(tm, sacc[1][r]);
        tm = fmaxf(tm, __shfl_xor(tm, 32, 64));
        if (!__all(tm <= m_r + 8.0f)) {          // defer-max (T13)
            const float mnew = fmaxf(m_r, tm);
            const float al   = __builtin_amdgcn_exp2f(m_r - mnew);
            m_r = mnew;
            lsum *= al;
#pragma unroll
            for (int dt = 0; dt < 2; ++dt)
#pragma unroll
                for (int r = 0; r < 16; ++r) oacc[dt][r] *= al;
        }
        float ps = 0.f;
#pragma unroll
        for (int st = 0; st < 2; ++st)
#pragma unroll
            for (int r = 0; r < 16; ++r) {
                const float p = __builtin_amdgcn_exp2f(sacc[st][r] - m_r);
                sacc[st][r] = p;
                ps += p;
            }
        lsum += ps;

        // ---- P -> bf16 B-fragments in-register (pack + permlane32_swap) ----
        // target word jj of pf[st*2+kk] = W[4kk+2h'+(jj&1)] from lane-half (jj>>1)
        bf16x8 pf[4];
#pragma unroll
        for (int st = 0; st < 2; ++st) {
            uint32_t W[8];
#pragma unroll
            for (int i = 0; i < 8; ++i) W[i] = pkbf(sacc[st][2 * i], sacc[st][2 * i + 1]);
#pragma unroll
            for (int kk = 0; kk < 2; ++kk) {
                uint32_t a0 = W[4 * kk + 0], b0 = W[4 * kk + 2];
                uint32_t a1 = W[4 * kk + 1], b1 = W[4 * kk + 3];
                asm volatile("v_permlane32_swap_b32 %0, %1" : "+v"(a0), "+v"(b0));
                asm volatile("v_permlane32_swap_b32 %0, %1" : "+v"(a1), "+v"(b1));
                union { uint32_t u[4]; bf16x8 v; } pu;
                pu.u[0] = a0; pu.u[1] = a1; pu.u[2] = b0; pu.u[3] = b1;
                pf[st * 2 + kk] = pu.v;
            }
        }

        // ---- PV (swapped): oacc[dt] += V^T-tile(32d x 16s) . P^T ----
        __builtin_amdgcn_s_setprio(1);
#pragma unroll
        for (int kt = 0; kt < 4; ++kt) {
#pragma unroll
            for (int dt = 0; dt < 2; ++dt) {
                bf16x8 vf = *(const bf16x8*)&Vl[buf][(dt * 32 + c) * 64 + (((kt * 2 + hh) ^ (c & 7)) * 8)];
                oacc[dt] = __builtin_amdgcn_mfma_f32_32x32x16_bf16(vf, pf[kt], oacc[dt], 0, 0, 0);
            }
        }
        __builtin_amdgcn_s_setprio(0);

        __syncthreads();   // next buffer staged (vmcnt drained), this buffer free
        buf ^= 1;
    }

    // ---- epilogue: reduce lsum across halves, normalize, store fp32 ----
    lsum += __shfl_xor(lsum, 32, 64);
    const float inv = 1.0f / lsum;
    float* op = Op + (size_t)(q0 + wave * 32 + c) * 512;
#pragma unroll
    for (int dt = 0; dt < 2; ++dt) {
#pragma unroll
        for (int rr = 0; rr < 4; ++rr) {
            float4 o = { oacc[dt][4 * rr + 0] * inv, oacc[dt][4 * rr + 1] * inv,
                         oacc[dt][4 * rr + 2] * inv, oacc[dt][4 * rr + 3] * inv };
            *(float4*)(op + dt * 32 + rr * 8 + hh * 4) = o;
        }
    }
}

extern "C" void kernel_launch(void* const* d_in, const int* in_sizes, int n_in,
                              void* d_out, int out_size, void* d_ws, size_t ws_size,
                              hipStream_t stream) {
    const float* Q = (const float*)d_in[0];
    const float* K = (const float*)d_in[1];
    const float* V = (const float*)d_in[2];
    float* Out = (float*)d_out;
    __bf16* Kb = (__bf16*)d_ws;
    __bf16* Vt = Kb + (size_t)NH * HEAD_ELEMS;   // 8 MB each, 16 MB total

    prep_k<<<dim3(4096), dim3(256), 0, stream>>>(K, Kb);
    prep_v<<<dim3(1024), dim3(256), 0, stream>>>(V, Vt);
    fattn <<<dim3(512),  dim3(256), 0, stream>>>(Q, Kb, Vt, Out);
}

// Round 4
// 70.952 us; speedup vs baseline: 1.7709x; 1.0646x over previous
//
#include <hip/hip_runtime.h>
#include <hip/hip_bf16.h>
#include <stdint.h>

// Full attention fwd: N=4, L=S=2048, H=8, D=64, fp32 in/out.
// Round 4: NO LDS in main loop. Prepass writes K/V bf16 in MFMA-fragment-major
// layout (per 64-row KV tile: 16 sections x 1KB; K sects 0..7 = st*4+ks,
// V sects 8..15 = dt*4+kt; within a section: lane-contiguous 16B chunks).
// Main kernel loads fragments global->VGPR (L2/L3-resident), zero barriers,
// 2-deep K prefetch + early V issue => natural counted-vmcnt pipeline.
// Swapped QK^T/PV with 32x32x16 MFMA, in-register P via pack+permlane32_swap,
// exp2 domain, defer-max, tree reductions, XCD swizzle.

typedef __bf16 bf16x8 __attribute__((ext_vector_type(8)));
typedef float  f32x16 __attribute__((ext_vector_type(16)));

#define N_ 4
#define L_ 2048
#define S_ 2048
#define H_ 8
#define D_ 64
#define NH 32
#define QBLK 128
#define KVBLK 64
#define NKV 32
#define TILE_BF16 8192                   // 16 sections * 512 bf16 (1KB) = 16KB
#define PLANE_BF16 (NKV * TILE_BF16)     // 512KB per (n,h) plane
#define SCALE_LOG2E 0.18033688011112042f // (1/sqrt(64)) * log2(e)

static __device__ __forceinline__ uint32_t pkbf(float lo, float hi) {
    uint16_t l = __builtin_bit_cast(uint16_t, (__bf16)lo);
    uint16_t h = __builtin_bit_cast(uint16_t, (__bf16)hi);
    return (uint32_t)l | ((uint32_t)h << 16);
}

// ---- prepass K: fp32 [n][s][h][d] -> fragment-major bf16 (sections 0..7) ----
__global__ __launch_bounds__(256) void prep_k(const float* __restrict__ K,
                                              __bf16* __restrict__ F) {
    const int ch   = blockIdx.x * 256 + threadIdx.x;  // 524288 16B-chunks
    const int nh   = ch >> 14;
    const int kv   = (ch >> 9) & 31;
    const int r    = ch & 511;
    const int sl   = r >> 3;              // s within tile, 0..63
    const int slot = r & 7;               // d octet
    const int n = nh >> 3, h = nh & 7;
    const float* p = K + ((size_t)(n * 2048 + kv * 64 + sl) * 8 + h) * 64 + slot * 8;
    float4 a = *(const float4*)p;
    float4 b = *(const float4*)(p + 4);
    bf16x8 v;
    v[0] = (__bf16)a.x; v[1] = (__bf16)a.y; v[2] = (__bf16)a.z; v[3] = (__bf16)a.w;
    v[4] = (__bf16)b.x; v[5] = (__bf16)b.y; v[6] = (__bf16)b.z; v[7] = (__bf16)b.w;
    const int st = sl >> 5, c = sl & 31, ks = slot >> 1, hh = slot & 1;
    *(bf16x8*)(F + (size_t)nh * PLANE_BF16 + kv * TILE_BF16
                 + (st * 4 + ks) * 512 + (hh * 32 + c) * 8) = v;
}

// ---- prepass V: fp32 [n][s][h][d] -> transposed fragment-major (sections 8..15) ----
__global__ __launch_bounds__(256) void prep_v(const float* __restrict__ V,
                                              __bf16* __restrict__ F) {
    __shared__ __align__(16) __bf16 T[64 * 64];
    const int tid = threadIdx.x;
    const int bid = blockIdx.x;          // nh*32 + kv
    const int nh  = bid >> 5;
    const int kv  = bid & 31;
    const int n   = nh >> 3, h = nh & 7;
    const int s0  = kv * 64;
#pragma unroll
    for (int it = 0; it < 16; ++it) {
        const int idx = it * 256 + tid;
        const int sl  = idx >> 6;
        const int d   = idx & 63;
        float v = V[(size_t)(n * 2048 + s0 + sl) * 512 + h * 64 + d];
        T[d * 64 + (((sl >> 3) ^ (d & 7)) * 8) + (sl & 7)] = (__bf16)v;
    }
    __syncthreads();
#pragma unroll
    for (int it = 0; it < 2; ++it) {
        const int idx = it * 256 + tid;   // 0..511
        const int d   = idx >> 3;
        const int sc  = idx & 7;
        bf16x8 v = *(const bf16x8*)&T[d * 64 + ((sc ^ (d & 7)) * 8)];
        const int dt = d >> 5, c = d & 31, kt = sc >> 1, hh = sc & 1;
        *(bf16x8*)(F + (size_t)nh * PLANE_BF16 + kv * TILE_BF16
                     + (8 + dt * 4 + kt) * 512 + (hh * 32 + c) * 8) = v;
    }
}

// ---------------- main attention kernel (no LDS, no barriers) ----------------
__global__ __launch_bounds__(256, 2) void fattn(const float* __restrict__ Q,
                                                const __bf16* __restrict__ F,
                                                float* __restrict__ Out) {
    const int tid  = threadIdx.x;
    const int wave = tid >> 6;
    const int lane = tid & 63;
    const int hh   = lane >> 5;
    const int c    = lane & 31;

    int bid = blockIdx.x;
    bid = (bid & 7) * 64 + (bid >> 3);   // XCD swizzle (512 % 8 == 0 -> bijective)
    const int nh = bid >> 4;
    const int qt = bid & 15;
    const int n  = nh >> 3, hd = nh & 7;
    const int q0 = qt * QBLK;

    const float*  Qp = Q   + (size_t)n * 1048576 + hd * 64;
    float*        Op = Out + (size_t)n * 1048576 + hd * 64;
    const __bf16* Pl = F + (size_t)nh * PLANE_BF16;

    // Q B-fragments (col = q = c, k = d = ks*16 + hh*8 + j), scaled
    bf16x8 qf[4];
    {
        const float* qp = Qp + (size_t)(q0 + wave * 32 + c) * 512;
#pragma unroll
        for (int ks = 0; ks < 4; ++ks) {
            float4 a = *(const float4*)(qp + ks * 16 + hh * 8);
            float4 b = *(const float4*)(qp + ks * 16 + hh * 8 + 4);
            bf16x8 v;
            v[0] = (__bf16)(a.x * SCALE_LOG2E); v[1] = (__bf16)(a.y * SCALE_LOG2E);
            v[2] = (__bf16)(a.z * SCALE_LOG2E); v[3] = (__bf16)(a.w * SCALE_LOG2E);
            v[4] = (__bf16)(b.x * SCALE_LOG2E); v[5] = (__bf16)(b.y * SCALE_LOG2E);
            v[6] = (__bf16)(b.z * SCALE_LOG2E); v[7] = (__bf16)(b.w * SCALE_LOG2E);
            qf[ks] = v;
        }
    }

    float m_r = -1e30f, lsum = 0.f;
    f32x16 oacc[2];
#pragma unroll
    for (int dt = 0; dt < 2; ++dt)
#pragma unroll
        for (int r = 0; r < 16; ++r) oacc[dt][r] = 0.f;

    bf16x8 kA[8], kB[8], vv[8];

    auto LK = [&](bf16x8 (&dst)[8], int kv) {
        const bf16x8* t = (const bf16x8*)(Pl + (size_t)kv * TILE_BF16);
#pragma unroll
        for (int f = 0; f < 8; ++f) dst[f] = t[f * 64 + lane];
    };
    auto LV = [&](bf16x8 (&dst)[8], int kv) {
        const bf16x8* t = (const bf16x8*)(Pl + (size_t)kv * TILE_BF16) + 512;
#pragma unroll
        for (int f = 0; f < 8; ++f) dst[f] = t[f * 64 + lane];
    };

    auto ITER = [&](bf16x8 (&kf)[8], bf16x8 (&vf)[8]) {
        // ---- QK^T (swapped): sacc[st] cols = q = c ----
        f32x16 sacc[2];
#pragma unroll
        for (int st = 0; st < 2; ++st)
#pragma unroll
            for (int r = 0; r < 16; ++r) sacc[st][r] = 0.f;
        __builtin_amdgcn_s_setprio(1);
#pragma unroll
        for (int ks = 0; ks < 4; ++ks)
#pragma unroll
            for (int st = 0; st < 2; ++st)
                sacc[st] = __builtin_amdgcn_mfma_f32_32x32x16_bf16(kf[st * 4 + ks], qf[ks], sacc[st], 0, 0, 0);
        __builtin_amdgcn_s_setprio(0);

        // ---- softmax: tree max over 32 values + cross-half shuffle ----
        float mx[16];
#pragma unroll
        for (int i = 0; i < 16; ++i) mx[i] = fmaxf(sacc[0][i], sacc[1][i]);
#pragma unroll
        for (int w = 8; w >= 1; w >>= 1)
#pragma unroll
            for (int i = 0; i < w; ++i) mx[i] = fmaxf(mx[i], mx[i + w]);
        float tm = fmaxf(mx[0], __shfl_xor(mx[0], 32, 64));
        if (!__all(tm <= m_r + 8.0f)) {       // defer-max (T13)
            const float mnew = fmaxf(m_r, tm);
            const float al   = __builtin_amdgcn_exp2f(m_r - mnew);
            m_r = mnew;
            lsum *= al;
#pragma unroll
            for (int dt = 0; dt < 2; ++dt)
#pragma unroll
                for (int r = 0; r < 16; ++r) oacc[dt][r] *= al;
        }
#pragma unroll
        for (int st = 0; st < 2; ++st)
#pragma unroll
            for (int r = 0; r < 16; ++r)
                sacc[st][r] = __builtin_amdgcn_exp2f(sacc[st][r] - m_r);
        float sm[16];
#pragma unroll
        for (int i = 0; i < 16; ++i) sm[i] = sacc[0][i] + sacc[1][i];
#pragma unroll
        for (int w = 8; w >= 1; w >>= 1)
#pragma unroll
            for (int i = 0; i < w; ++i) sm[i] += sm[i + w];
        lsum += sm[0];

        // ---- P -> bf16 B-fragments in-register (pack + permlane32_swap) ----
        bf16x8 pf[4];
#pragma unroll
        for (int st = 0; st < 2; ++st) {
            uint32_t W[8];
#pragma unroll
            for (int i = 0; i < 8; ++i) W[i] = pkbf(sacc[st][2 * i], sacc[st][2 * i + 1]);
#pragma unroll
            for (int kk = 0; kk < 2; ++kk) {
                uint32_t a0 = W[4 * kk + 0], b0 = W[4 * kk + 2];
                uint32_t a1 = W[4 * kk + 1], b1 = W[4 * kk + 3];
                asm volatile("v_permlane32_swap_b32 %0, %1" : "+v"(a0), "+v"(b0));
                asm volatile("v_permlane32_swap_b32 %0, %1" : "+v"(a1), "+v"(b1));
                union { uint32_t u[4]; bf16x8 v; } pu;
                pu.u[0] = a0; pu.u[1] = a1; pu.u[2] = b0; pu.u[3] = b1;
                pf[st * 2 + kk] = pu.v;
            }
        }

        // ---- PV (swapped): oacc[dt] += V^T-frag . P^T ----
        __builtin_amdgcn_s_setprio(1);
#pragma unroll
        for (int kt = 0; kt < 4; ++kt)
#pragma unroll
            for (int dt = 0; dt < 2; ++dt)
                oacc[dt] = __builtin_amdgcn_mfma_f32_32x32x16_bf16(vf[dt * 4 + kt], pf[kt], oacc[dt], 0, 0, 0);
        __builtin_amdgcn_s_setprio(0);
    };

    LK(kA, 0);
    for (int kv = 0; kv < NKV; kv += 2) {
        LV(vv, kv);                              // used ~QK^T+softmax later
        LK(kB, kv + 1);                          // used next half-iter
        ITER(kA, vv);
        LV(vv, kv + 1);
        LK(kA, kv + 2 < NKV ? kv + 2 : NKV - 1); // clamped redundant load at tail
        ITER(kB, vv);
    }

    // ---- epilogue: reduce lsum across halves, normalize, store fp32 ----
    lsum += __shfl_xor(lsum, 32, 64);
    const float inv = 1.0f / lsum;
    float* op = Op + (size_t)(q0 + wave * 32 + c) * 512;
#pragma unroll
    for (int dt = 0; dt < 2; ++dt) {
#pragma unroll
        for (int rr = 0; rr < 4; ++rr) {
            float4 o = { oacc[dt][4 * rr + 0] * inv, oacc[dt][4 * rr + 1] * inv,
                         oacc[dt][4 * rr + 2] * inv, oacc[dt][4 * rr + 3] * inv };
            *(float4*)(op + dt * 32 + rr * 8 + hh * 4) = o;
        }
    }
}

extern "C" void kernel_launch(void* const* d_in, const int* in_sizes, int n_in,
                              void* d_out, int out_size, void* d_ws, size_t ws_size,
                              hipStream_t stream) {
    const float* Q = (const float*)d_in[0];
    const float* K = (const float*)d_in[1];
    const float* V = (const float*)d_in[2];
    float* Out = (float*)d_out;
    __bf16* F = (__bf16*)d_ws;   // 16 MB fragment-major K+V

    prep_k<<<dim3(2048), dim3(256), 0, stream>>>(K, F);
    prep_v<<<dim3(1024), dim3(256), 0, stream>>>(V, F);
    fattn <<<dim3(512),  dim3(256), 0, stream>>>(Q, F, Out);
}